// Round 1
// baseline (444.077 us; speedup 1.0000x reference)
//
#include <hip/hip_runtime.h>
#include <hip/hip_bf16.h>

#define NN 512
#define MM (NN*NN)   // 262144 rows

typedef __attribute__((ext_vector_type(8))) unsigned short u16x8;
typedef __attribute__((ext_vector_type(4))) unsigned short u16x4;
typedef __attribute__((ext_vector_type(8))) __bf16 bf16x8;
typedef __attribute__((ext_vector_type(4))) float f32x4;

static __device__ __forceinline__ unsigned short f2bf(float f) {
  unsigned int u = __float_as_uint(f);
  u = (u + 0x7FFFu + ((u >> 16) & 1u)) >> 16;
  return (unsigned short)u;
}
static __device__ __forceinline__ float bf2f(unsigned short h) {
  return __uint_as_float(((unsigned int)h) << 16);
}
static __device__ __forceinline__ bf16x8 ldfrag(const unsigned short* p) {
  u16x8 v = *(const u16x8*)p;
  return __builtin_bit_cast(bf16x8, v);
}
static __device__ __forceinline__ float sigm(float x) {
  return 1.0f / (1.0f + __expf(-x));
}

// ---------------- prep: WT[n][k] (bf16), n: [ga|la|gb|lb|g|lu] x 128 cols, k = 128 ----
__global__ void prep_weights(const float* __restrict__ ga_w, const float* __restrict__ la_w,
                             const float* __restrict__ gb_w, const float* __restrict__ lb_w,
                             const float* __restrict__ g_w,  const float* __restrict__ lu_w,
                             unsigned short* __restrict__ WT) {
  int idx = blockIdx.x * 256 + threadIdx.x;
  if (idx >= 768 * 128) return;
  int n = idx >> 7;     // output row (col of original weight)
  int k = idx & 127;    // reduction index
  int grp = n >> 7, cn = n & 127;
  const float* tabs[6] = {ga_w, la_w, gb_w, lb_w, g_w, lu_w};
  WT[idx] = f2bf(tabs[grp][k * 128 + cn]);
}

// ---------------- K1: fused LN + 5 projections -----------------------------------------
// grid.x = M/64, grid.y = 3 (0: a, 1: b, 2: g)
__global__ __launch_bounds__(256) void k1_proj(
    const float* __restrict__ pair, const float* __restrict__ lng, const float* __restrict__ lnb,
    const unsigned short* __restrict__ WT,
    const float* __restrict__ ga_b, const float* __restrict__ la_b,
    const float* __restrict__ gb_b, const float* __restrict__ lb_b,
    const float* __restrict__ g_b,
    unsigned short* __restrict__ a_t, unsigned short* __restrict__ b_t,
    unsigned short* __restrict__ g_buf) {
  __shared__ __align__(16) unsigned short sA[64 * 136];
  __shared__ __align__(16) unsigned short sB[128 * 136];
  const int t = threadIdx.x;
  const int y = blockIdx.y;
  const size_t m0 = (size_t)blockIdx.x * 64;

  // Phase A: LayerNorm 64 rows of pair_rep -> sA bf16
  {
    const int row = t >> 2, q = t & 3;
    const float* pr = pair + (m0 + row) * 128 + q * 32;
    float vals[32];
    float s = 0.f, ss = 0.f;
#pragma unroll
    for (int it = 0; it < 8; ++it) {
      f32x4 v = *(const f32x4*)(pr + it * 4);
#pragma unroll
      for (int j = 0; j < 4; ++j) { float x = v[j]; vals[it * 4 + j] = x; s += x; ss += x * x; }
    }
    s += __shfl_xor(s, 1);  s += __shfl_xor(s, 2);
    ss += __shfl_xor(ss, 1); ss += __shfl_xor(ss, 2);
    const float mean = s * (1.f / 128.f);
    const float var  = ss * (1.f / 128.f) - mean * mean;
    const float rstd = rsqrtf(var + 1e-5f);
#pragma unroll
    for (int j = 0; j < 32; ++j) {
      int c = q * 32 + j;
      float zn = (vals[j] - mean) * rstd * lng[c] + lnb[c];
      sA[row * 136 + c] = f2bf(zn);
    }
  }

  const int wave = t >> 6, lane = t & 63, lrow = lane & 15, qk = lane >> 4;
  const int ngemm = (y == 2) ? 1 : 2;
  const int base0 = (y == 2) ? 512 : y * 256;

  f32x4 accg[8], accl[8];
#pragma unroll
  for (int i = 0; i < 8; ++i) {
#pragma unroll
    for (int r = 0; r < 4; ++r) { accg[i][r] = 0.f; accl[i][r] = 0.f; }
  }

  for (int gsel = 0; gsel < ngemm; ++gsel) {
    __syncthreads();   // waves done with sB (and sA ready on first pass)
    const int base = base0 + gsel * 128;
#pragma unroll
    for (int it = 0; it < 8; ++it) {
      int idx = it * 256 + t;
      int n = idx >> 4, off = (idx & 15) * 8;
      *(u16x8*)(sB + n * 136 + off) = *(const u16x8*)(WT + (size_t)(base + n) * 128 + off);
    }
    __syncthreads();
    f32x4* acc = gsel ? accl : accg;
#pragma unroll
    for (int ks = 0; ks < 4; ++ks) {
      int k0 = ks * 32;
      bf16x8 af = ldfrag(sA + (wave * 16 + lrow) * 136 + k0 + 8 * qk);
#pragma unroll
      for (int nt = 0; nt < 8; ++nt) {
        bf16x8 bv = ldfrag(sB + (nt * 16 + lrow) * 136 + k0 + 8 * qk);
        acc[nt] = __builtin_amdgcn_mfma_f32_16x16x32_bf16(af, bv, acc[nt], 0, 0, 0);
      }
    }
  }
  __syncthreads();   // all waves done reading sA/sB before overlay

  if (y < 2) {
    const float* gbias = (y == 0) ? ga_b : gb_b;
    const float* lbias = (y == 0) ? la_b : lb_b;
    unsigned short* outT = sB;   // [128][72] transposed staging
#pragma unroll
    for (int nt = 0; nt < 8; ++nt) {
      int col = nt * 16 + lrow;
      float bg = gbias[col], bl = lbias[col];
      u16x4 pk;
#pragma unroll
      for (int r = 0; r < 4; ++r) {
        float av = sigm(accg[nt][r] + bg) * (accl[nt][r] + bl);
        pk[r] = f2bf(av);
      }
      *(u16x4*)(outT + col * 72 + wave * 16 + qk * 4) = pk;
    }
    __syncthreads();
    unsigned short* dst = (y == 0) ? a_t : b_t;
    int col = t >> 1, half = t & 1;
    const unsigned short* srcp = outT + col * 72 + half * 32;
    unsigned short* dp = dst + (size_t)col * MM + m0 + half * 32;
#pragma unroll
    for (int j = 0; j < 4; ++j)
      *(u16x8*)(dp + j * 8) = *(const u16x8*)(srcp + j * 8);
  } else {
    unsigned short* outG = sA;   // [64][136] row-major staging
#pragma unroll
    for (int nt = 0; nt < 8; ++nt) {
      int col = nt * 16 + lrow;
      float bg = g_b[col];
#pragma unroll
      for (int r = 0; r < 4; ++r) {
        float gv = sigm(accg[nt][r] + bg);
        outG[(wave * 16 + qk * 4 + r) * 136 + col] = f2bf(gv);
      }
    }
    __syncthreads();
#pragma unroll
    for (int it = 0; it < 4; ++it) {
      int idx = it * 256 + t;
      int mr = idx >> 4, off = (idx & 15) * 8;
      *(u16x8*)(g_buf + (m0 + mr) * 128 + off) = *(const u16x8*)(outG + mr * 136 + off);
    }
  }
}

// ---------------- K2: channel-batched NT GEMM update_t[c] = A_c * B_c^T ----------------
// grid.x = 16 (4x4 tiles of 128), grid.y = 128 (channel)
__global__ __launch_bounds__(256) void k2_einsum(
    const unsigned short* __restrict__ a_t, const unsigned short* __restrict__ b_t,
    unsigned short* __restrict__ up_t) {
  __shared__ __align__(16) unsigned short sA[128 * 40];
  __shared__ __align__(16) unsigned short sB[128 * 40];
  const int t = threadIdx.x;
  const int c = blockIdx.y;
  const int i0 = (blockIdx.x >> 2) * 128, j0 = (blockIdx.x & 3) * 128;
  const unsigned short* Ag = a_t + (size_t)c * MM + (size_t)i0 * 512;
  const unsigned short* Bg = b_t + (size_t)c * MM + (size_t)j0 * 512;
  const int wave = t >> 6, lane = t & 63, wr = wave >> 1, wc = wave & 1;
  const int lrow = lane & 15, qk = lane >> 4;
  f32x4 acc[4][4];
#pragma unroll
  for (int i = 0; i < 4; ++i)
#pragma unroll
    for (int j = 0; j < 4; ++j)
#pragma unroll
      for (int r = 0; r < 4; ++r) acc[i][j][r] = 0.f;

  for (int ks = 0; ks < 16; ++ks) {
    const int k0 = ks * 32;
#pragma unroll
    for (int h = 0; h < 2; ++h) {
      int idx = h * 256 + t;
      int row = idx >> 2, qq = idx & 3;
      *(u16x8*)(sA + row * 40 + qq * 8) = *(const u16x8*)(Ag + (size_t)row * 512 + k0 + qq * 8);
      *(u16x8*)(sB + row * 40 + qq * 8) = *(const u16x8*)(Bg + (size_t)row * 512 + k0 + qq * 8);
    }
    __syncthreads();
    bf16x8 af[4], bv[4];
#pragma unroll
    for (int mt = 0; mt < 4; ++mt)
      af[mt] = ldfrag(sA + (wr * 64 + mt * 16 + lrow) * 40 + 8 * qk);
#pragma unroll
    for (int nt = 0; nt < 4; ++nt)
      bv[nt] = ldfrag(sB + (wc * 64 + nt * 16 + lrow) * 40 + 8 * qk);
#pragma unroll
    for (int mt = 0; mt < 4; ++mt)
#pragma unroll
      for (int nt = 0; nt < 4; ++nt)
        acc[mt][nt] = __builtin_amdgcn_mfma_f32_16x16x32_bf16(af[mt], bv[nt], acc[mt][nt], 0, 0, 0);
    __syncthreads();
  }
  unsigned short* up = up_t + (size_t)c * MM;
#pragma unroll
  for (int mt = 0; mt < 4; ++mt)
#pragma unroll
    for (int nt = 0; nt < 4; ++nt) {
      int col = j0 + wc * 64 + nt * 16 + lrow;
#pragma unroll
      for (int r = 0; r < 4; ++r) {
        int row = i0 + wr * 64 + mt * 16 + qk * 4 + r;
        up[(size_t)row * 512 + col] = f2bf(acc[mt][nt][r]);
      }
    }
}

// ---------------- K3: LN(update) @ lu_w + lu_b, * g -> out -----------------------------
// grid.x = M/64
__global__ __launch_bounds__(256) void k3_final(
    const unsigned short* __restrict__ up_t, const unsigned short* __restrict__ g_buf,
    const unsigned short* __restrict__ WT,
    const float* __restrict__ lnug, const float* __restrict__ lnub,
    const float* __restrict__ lu_b, float* __restrict__ out) {
  __shared__ __align__(16) unsigned short sU[64 * 138];
  __shared__ __align__(16) unsigned short sA[64 * 136];
  __shared__ __align__(16) unsigned short sB[128 * 136];
  const int t = threadIdx.x;
  const size_t m0 = (size_t)blockIdx.x * 64;
  // load update tile: per channel c, 64 consecutive m (coalesced 128B runs)
#pragma unroll
  for (int it = 0; it < 4; ++it) {
    int idx = it * 256 + t;
    int c = idx >> 3, m8 = (idx & 7) * 8;
    u16x8 v = *(const u16x8*)(up_t + (size_t)c * MM + m0 + m8);
#pragma unroll
    for (int j = 0; j < 8; ++j) sU[(m8 + j) * 138 + c] = v[j];
  }
  // load lu_wT (WT rows 640..767)
#pragma unroll
  for (int it = 0; it < 8; ++it) {
    int idx = it * 256 + t;
    int n = idx >> 4, off = (idx & 15) * 8;
    *(u16x8*)(sB + n * 136 + off) = *(const u16x8*)(WT + (size_t)(640 + n) * 128 + off);
  }
  __syncthreads();
  {
    const int row = t >> 2, q = t & 3;
    float vals[32]; float s = 0.f, ss = 0.f;
#pragma unroll
    for (int jj = 0; jj < 32; ++jj) {
      int cc = q + jj * 4;
      float x = bf2f(sU[row * 138 + cc]);
      vals[jj] = x; s += x; ss += x * x;
    }
    s += __shfl_xor(s, 1);  s += __shfl_xor(s, 2);
    ss += __shfl_xor(ss, 1); ss += __shfl_xor(ss, 2);
    float mean = s * (1.f / 128.f);
    float var  = ss * (1.f / 128.f) - mean * mean;
    float rstd = rsqrtf(var + 1e-5f);
#pragma unroll
    for (int jj = 0; jj < 32; ++jj) {
      int cc = q + jj * 4;
      float zn = (vals[jj] - mean) * rstd * lnug[cc] + lnub[cc];
      sA[row * 136 + cc] = f2bf(zn);
    }
  }
  __syncthreads();
  const int wave = t >> 6, lane = t & 63, lrow = lane & 15, qk = lane >> 4;
  f32x4 acc[8];
#pragma unroll
  for (int i = 0; i < 8; ++i)
#pragma unroll
    for (int r = 0; r < 4; ++r) acc[i][r] = 0.f;
#pragma unroll
  for (int ks = 0; ks < 4; ++ks) {
    int k0 = ks * 32;
    bf16x8 af = ldfrag(sA + (wave * 16 + lrow) * 136 + k0 + 8 * qk);
#pragma unroll
    for (int nt = 0; nt < 8; ++nt) {
      bf16x8 bv = ldfrag(sB + (nt * 16 + lrow) * 136 + k0 + 8 * qk);
      acc[nt] = __builtin_amdgcn_mfma_f32_16x16x32_bf16(af, bv, acc[nt], 0, 0, 0);
    }
  }
#pragma unroll
  for (int nt = 0; nt < 8; ++nt) {
    int e = nt * 16 + lrow;
    float bb = lu_b[e];
#pragma unroll
    for (int r = 0; r < 4; ++r) {
      size_t m = m0 + wave * 16 + qk * 4 + r;
      float lin = acc[nt][r] + bb;
      float gv = bf2f(g_buf[m * 128 + e]);
      out[m * 128 + e] = gv * lin;
    }
  }
}

extern "C" void kernel_launch(void* const* d_in, const int* in_sizes, int n_in,
                              void* d_out, int out_size, void* d_ws, size_t ws_size,
                              hipStream_t stream) {
  const float* pair = (const float*)d_in[0];
  const float* lng  = (const float*)d_in[1];
  const float* lnb  = (const float*)d_in[2];
  const float* ga_w = (const float*)d_in[3];
  const float* ga_b = (const float*)d_in[4];
  const float* la_w = (const float*)d_in[5];
  const float* la_b = (const float*)d_in[6];
  const float* gb_w = (const float*)d_in[7];
  const float* gb_b = (const float*)d_in[8];
  const float* lb_w = (const float*)d_in[9];
  const float* lb_b = (const float*)d_in[10];
  const float* g_w  = (const float*)d_in[11];
  const float* g_b  = (const float*)d_in[12];
  const float* lnug = (const float*)d_in[13];
  const float* lnub = (const float*)d_in[14];
  const float* lu_w = (const float*)d_in[15];
  const float* lu_b = (const float*)d_in[16];
  float* out = (float*)d_out;

  char* ws = (char*)d_ws;
  unsigned short* WT    = (unsigned short*)(ws);                  // 768*128*2   = 196608 B
  unsigned short* a_t   = (unsigned short*)(ws + 196608ull);      // 128*M*2     = 67108864 B
  unsigned short* b_t   = (unsigned short*)(ws + 67305472ull);    // 128*M*2
  unsigned short* g_buf = (unsigned short*)(ws + 134414336ull);   // M*128*2
  unsigned short* up_t  = (unsigned short*)(ws + 201523200ull);   // 128*M*2  (total ~268.6 MB)

  hipLaunchKernelGGL(prep_weights, dim3(384), dim3(256), 0, stream,
                     ga_w, la_w, gb_w, lb_w, g_w, lu_w, WT);
  hipLaunchKernelGGL(k1_proj, dim3(4096, 3), dim3(256), 0, stream,
                     pair, lng, lnb, WT, ga_b, la_b, gb_b, lb_b, g_b, a_t, b_t, g_buf);
  hipLaunchKernelGGL(k2_einsum, dim3(16, 128), dim3(256), 0, stream, a_t, b_t, up_t);
  hipLaunchKernelGGL(k3_final, dim3(4096), dim3(256), 0, stream,
                     up_t, g_buf, WT, lnug, lnub, lu_b, out);
}

// Round 2
// 315.203 us; speedup vs baseline: 1.4089x; 1.4089x over previous
//
#include <hip/hip_runtime.h>
#include <hip/hip_bf16.h>

#define NN 512
#define MM (NN*NN)   // 262144 rows

typedef __attribute__((ext_vector_type(8))) unsigned short u16x8;
typedef __attribute__((ext_vector_type(4))) unsigned short u16x4;
typedef __attribute__((ext_vector_type(8))) __bf16 bf16x8;
typedef __attribute__((ext_vector_type(4))) float f32x4;

static __device__ __forceinline__ unsigned short f2bf(float f) {
  unsigned int u = __float_as_uint(f);
  u = (u + 0x7FFFu + ((u >> 16) & 1u)) >> 16;
  return (unsigned short)u;
}
static __device__ __forceinline__ float bf2f(unsigned short h) {
  return __uint_as_float(((unsigned int)h) << 16);
}
static __device__ __forceinline__ bf16x8 ldfrag(const unsigned short* p) {
  u16x8 v = *(const u16x8*)p;
  return __builtin_bit_cast(bf16x8, v);
}
static __device__ __forceinline__ float sigm(float x) {
  return 1.0f / (1.0f + __expf(-x));
}

// ---------------- prep: WT[n][k] (bf16), n: [ga|la|gb|lb|g|lu] x 128 cols, k = 128 ----
__global__ void prep_weights(const float* __restrict__ ga_w, const float* __restrict__ la_w,
                             const float* __restrict__ gb_w, const float* __restrict__ lb_w,
                             const float* __restrict__ g_w,  const float* __restrict__ lu_w,
                             unsigned short* __restrict__ WT) {
  int idx = blockIdx.x * 256 + threadIdx.x;
  if (idx >= 768 * 128) return;
  int n = idx >> 7;     // output row (col of original weight)
  int k = idx & 127;    // reduction index
  int grp = n >> 7, cn = n & 127;
  const float* tabs[6] = {ga_w, la_w, gb_w, lb_w, g_w, lu_w};
  WT[idx] = f2bf(tabs[grp][k * 128 + cn]);
}

// ---------------- K1: fused LN + ALL 5 projections (merged slices) ---------------------
// grid.x = M/128, block = 512 (8 waves), each wave owns 16 rows x 128 cols per GEMM
__global__ __launch_bounds__(512, 4) void k1_proj(
    const float* __restrict__ pair, const float* __restrict__ lng, const float* __restrict__ lnb,
    const unsigned short* __restrict__ WT,
    const float* __restrict__ ga_b, const float* __restrict__ la_b,
    const float* __restrict__ gb_b, const float* __restrict__ lb_b,
    const float* __restrict__ g_b,
    unsigned short* __restrict__ a_t, unsigned short* __restrict__ b_t,
    unsigned short* __restrict__ g_buf) {
  __shared__ __align__(16) unsigned short sA[128 * 136];
  __shared__ __align__(16) unsigned short sB[128 * 136];
  const int t = threadIdx.x;
  const size_t m0 = (size_t)blockIdx.x * 128;

  // ---- Phase LN: normalize 128 rows of pair_rep -> sA (bf16), done ONCE ----
  {
    const int row = t >> 2, q = t & 3;
    const float* pr = pair + (m0 + row) * 128 + q * 32;
    float vals[32];
    float s = 0.f, ss = 0.f;
#pragma unroll
    for (int it = 0; it < 8; ++it) {
      f32x4 v = *(const f32x4*)(pr + it * 4);
#pragma unroll
      for (int j = 0; j < 4; ++j) { float x = v[j]; vals[it * 4 + j] = x; s += x; ss += x * x; }
    }
    s += __shfl_xor(s, 1);  s += __shfl_xor(s, 2);
    ss += __shfl_xor(ss, 1); ss += __shfl_xor(ss, 2);
    const float mean = s * (1.f / 128.f);
    const float var  = ss * (1.f / 128.f) - mean * mean;
    const float rstd = rsqrtf(var + 1e-5f);
#pragma unroll
    for (int i = 0; i < 4; ++i) {
      u16x8 pk;
#pragma unroll
      for (int j = 0; j < 8; ++j) {
        int c = q * 32 + i * 8 + j;
        pk[j] = f2bf((vals[i * 8 + j] - mean) * rstd * lng[c] + lnb[c]);
      }
      *(u16x8*)(sA + row * 136 + q * 32 + i * 8) = pk;
    }
  }
  __syncthreads();

  const int wave = t >> 6, lane = t & 63, lrow = lane & 15, qk = lane >> 4;

  // A-fragments for this wave's 16 rows: load once, reuse across all 5 GEMMs
  bf16x8 af[4];
#pragma unroll
  for (int ks = 0; ks < 4; ++ks)
    af[ks] = ldfrag(sA + (wave * 16 + lrow) * 136 + ks * 32 + 8 * qk);

  f32x4 accg[8], accl[8];

  // ---- passes 0,1: (ga,la) -> a_t ; (gb,lb) -> b_t ----
  for (int pass = 0; pass < 2; ++pass) {
#pragma unroll
    for (int sub = 0; sub < 2; ++sub) {
      __syncthreads();   // prior readers of sB done
      const int base = pass * 256 + sub * 128;
#pragma unroll
      for (int it = 0; it < 4; ++it) {
        int idx = it * 512 + t;
        int n = idx >> 4, off = (idx & 15) * 8;
        *(u16x8*)(sB + n * 136 + off) = *(const u16x8*)(WT + (size_t)(base + n) * 128 + off);
      }
      __syncthreads();
      f32x4* acc = sub ? accl : accg;
#pragma unroll
      for (int nt = 0; nt < 8; ++nt)
#pragma unroll
        for (int r = 0; r < 4; ++r) acc[nt][r] = 0.f;
#pragma unroll
      for (int ks = 0; ks < 4; ++ks) {
#pragma unroll
        for (int nt = 0; nt < 8; ++nt) {
          bf16x8 bv = ldfrag(sB + (nt * 16 + lrow) * 136 + ks * 32 + 8 * qk);
          acc[nt] = __builtin_amdgcn_mfma_f32_16x16x32_bf16(af[ks], bv, acc[nt], 0, 0, 0);
        }
      }
    }
    // epilogue: a = sigmoid(zg+bg)*(zl+bl), stage transposed [col][128] in sB, write out
    __syncthreads();   // all waves done reading sB
    {
      const float* gbias = (pass == 0) ? ga_b : gb_b;
      const float* lbias = (pass == 0) ? la_b : lb_b;
#pragma unroll
      for (int nt = 0; nt < 8; ++nt) {
        int col = nt * 16 + lrow;
        float bg = gbias[col], bl = lbias[col];
        u16x4 pk;
#pragma unroll
        for (int r = 0; r < 4; ++r)
          pk[r] = f2bf(sigm(accg[nt][r] + bg) * (accl[nt][r] + bl));
        *(u16x4*)(sB + col * 136 + wave * 16 + qk * 4) = pk;
      }
    }
    __syncthreads();
    {
      unsigned short* dst = (pass == 0) ? a_t : b_t;
#pragma unroll
      for (int it = 0; it < 4; ++it) {
        int idx = it * 512 + t;
        int col = idx >> 4, i = idx & 15;
        *(u16x8*)(dst + (size_t)col * MM + m0 + i * 8) = *(const u16x8*)(sB + col * 136 + i * 8);
      }
    }
  }

  // ---- pass g: sigmoid(z@g_w + g_b) -> g_buf (row-major [m][128]) ----
  __syncthreads();
#pragma unroll
  for (int it = 0; it < 4; ++it) {
    int idx = it * 512 + t;
    int n = idx >> 4, off = (idx & 15) * 8;
    *(u16x8*)(sB + n * 136 + off) = *(const u16x8*)(WT + (size_t)(512 + n) * 128 + off);
  }
  __syncthreads();
#pragma unroll
  for (int nt = 0; nt < 8; ++nt)
#pragma unroll
    for (int r = 0; r < 4; ++r) accg[nt][r] = 0.f;
#pragma unroll
  for (int ks = 0; ks < 4; ++ks) {
#pragma unroll
    for (int nt = 0; nt < 8; ++nt) {
      bf16x8 bv = ldfrag(sB + (nt * 16 + lrow) * 136 + ks * 32 + 8 * qk);
      accg[nt] = __builtin_amdgcn_mfma_f32_16x16x32_bf16(af[ks], bv, accg[nt], 0, 0, 0);
    }
  }
  __syncthreads();   // done reading sB
#pragma unroll
  for (int nt = 0; nt < 8; ++nt) {
    int col = nt * 16 + lrow;
    float bg = g_b[col];
#pragma unroll
    for (int r = 0; r < 4; ++r)
      sB[(wave * 16 + qk * 4 + r) * 136 + col] = f2bf(sigm(accg[nt][r] + bg));
  }
  __syncthreads();
#pragma unroll
  for (int it = 0; it < 4; ++it) {
    int idx = it * 512 + t;
    int mr = idx >> 4, off = (idx & 15) * 8;
    *(u16x8*)(g_buf + (m0 + mr) * 128 + off) = *(const u16x8*)(sB + mr * 136 + off);
  }
}

// ---------------- K2: channel-batched NT GEMM update_t[c] = A_c * B_c^T ----------------
// grid.x = 16 (4x4 tiles of 128), grid.y = 128 (channel)
__global__ __launch_bounds__(256) void k2_einsum(
    const unsigned short* __restrict__ a_t, const unsigned short* __restrict__ b_t,
    unsigned short* __restrict__ up_t) {
  __shared__ __align__(16) unsigned short sA[128 * 40];
  __shared__ __align__(16) unsigned short sB[128 * 40];
  const int t = threadIdx.x;
  const int c = blockIdx.y;
  const int i0 = (blockIdx.x >> 2) * 128, j0 = (blockIdx.x & 3) * 128;
  const unsigned short* Ag = a_t + (size_t)c * MM + (size_t)i0 * 512;
  const unsigned short* Bg = b_t + (size_t)c * MM + (size_t)j0 * 512;
  const int wave = t >> 6, lane = t & 63, wr = wave >> 1, wc = wave & 1;
  const int lrow = lane & 15, qk = lane >> 4;
  f32x4 acc[4][4];
#pragma unroll
  for (int i = 0; i < 4; ++i)
#pragma unroll
    for (int j = 0; j < 4; ++j)
#pragma unroll
      for (int r = 0; r < 4; ++r) acc[i][j][r] = 0.f;

  for (int ks = 0; ks < 16; ++ks) {
    const int k0 = ks * 32;
#pragma unroll
    for (int h = 0; h < 2; ++h) {
      int idx = h * 256 + t;
      int row = idx >> 2, qq = idx & 3;
      *(u16x8*)(sA + row * 40 + qq * 8) = *(const u16x8*)(Ag + (size_t)row * 512 + k0 + qq * 8);
      *(u16x8*)(sB + row * 40 + qq * 8) = *(const u16x8*)(Bg + (size_t)row * 512 + k0 + qq * 8);
    }
    __syncthreads();
    bf16x8 af[4], bv[4];
#pragma unroll
    for (int mt = 0; mt < 4; ++mt)
      af[mt] = ldfrag(sA + (wr * 64 + mt * 16 + lrow) * 40 + 8 * qk);
#pragma unroll
    for (int nt = 0; nt < 4; ++nt)
      bv[nt] = ldfrag(sB + (wc * 64 + nt * 16 + lrow) * 40 + 8 * qk);
#pragma unroll
    for (int mt = 0; mt < 4; ++mt)
#pragma unroll
      for (int nt = 0; nt < 4; ++nt)
        acc[mt][nt] = __builtin_amdgcn_mfma_f32_16x16x32_bf16(af[mt], bv[nt], acc[mt][nt], 0, 0, 0);
    __syncthreads();
  }
  unsigned short* up = up_t + (size_t)c * MM;
#pragma unroll
  for (int mt = 0; mt < 4; ++mt)
#pragma unroll
    for (int nt = 0; nt < 4; ++nt) {
      int col = j0 + wc * 64 + nt * 16 + lrow;
#pragma unroll
      for (int r = 0; r < 4; ++r) {
        int row = i0 + wr * 64 + mt * 16 + qk * 4 + r;
        up[(size_t)row * 512 + col] = f2bf(acc[mt][nt][r]);
      }
    }
}

// ---------------- K3: LN(update) @ lu_w + lu_b, * g -> out -----------------------------
// grid.x = M/64
__global__ __launch_bounds__(256) void k3_final(
    const unsigned short* __restrict__ up_t, const unsigned short* __restrict__ g_buf,
    const unsigned short* __restrict__ WT,
    const float* __restrict__ lnug, const float* __restrict__ lnub,
    const float* __restrict__ lu_b, float* __restrict__ out) {
  __shared__ __align__(16) unsigned short sU[64 * 138];
  __shared__ __align__(16) unsigned short sA[64 * 136];
  __shared__ __align__(16) unsigned short sB[128 * 136];
  const int t = threadIdx.x;
  const size_t m0 = (size_t)blockIdx.x * 64;
  // load update tile: per channel c, 64 consecutive m (coalesced 128B runs)
#pragma unroll
  for (int it = 0; it < 4; ++it) {
    int idx = it * 256 + t;
    int c = idx >> 3, m8 = (idx & 7) * 8;
    u16x8 v = *(const u16x8*)(up_t + (size_t)c * MM + m0 + m8);
#pragma unroll
    for (int j = 0; j < 8; ++j) sU[(m8 + j) * 138 + c] = v[j];
  }
  // load lu_wT (WT rows 640..767)
#pragma unroll
  for (int it = 0; it < 8; ++it) {
    int idx = it * 256 + t;
    int n = idx >> 4, off = (idx & 15) * 8;
    *(u16x8*)(sB + n * 136 + off) = *(const u16x8*)(WT + (size_t)(640 + n) * 128 + off);
  }
  __syncthreads();
  {
    const int row = t >> 2, q = t & 3;
    float vals[32]; float s = 0.f, ss = 0.f;
#pragma unroll
    for (int jj = 0; jj < 32; ++jj) {
      int cc = q + jj * 4;
      float x = bf2f(sU[row * 138 + cc]);
      vals[jj] = x; s += x; ss += x * x;
    }
    s += __shfl_xor(s, 1);  s += __shfl_xor(s, 2);
    ss += __shfl_xor(ss, 1); ss += __shfl_xor(ss, 2);
    float mean = s * (1.f / 128.f);
    float var  = ss * (1.f / 128.f) - mean * mean;
    float rstd = rsqrtf(var + 1e-5f);
#pragma unroll
    for (int jj = 0; jj < 32; ++jj) {
      int cc = q + jj * 4;
      float zn = (vals[jj] - mean) * rstd * lnug[cc] + lnub[cc];
      sA[row * 136 + cc] = f2bf(zn);
    }
  }
  __syncthreads();
  const int wave = t >> 6, lane = t & 63, lrow = lane & 15, qk = lane >> 4;
  f32x4 acc[8];
#pragma unroll
  for (int i = 0; i < 8; ++i)
#pragma unroll
    for (int r = 0; r < 4; ++r) acc[i][r] = 0.f;
#pragma unroll
  for (int ks = 0; ks < 4; ++ks) {
    int k0 = ks * 32;
    bf16x8 af = ldfrag(sA + (wave * 16 + lrow) * 136 + k0 + 8 * qk);
#pragma unroll
    for (int nt = 0; nt < 8; ++nt) {
      bf16x8 bv = ldfrag(sB + (nt * 16 + lrow) * 136 + k0 + 8 * qk);
      acc[nt] = __builtin_amdgcn_mfma_f32_16x16x32_bf16(af, bv, acc[nt], 0, 0, 0);
    }
  }
#pragma unroll
  for (int nt = 0; nt < 8; ++nt) {
    int e = nt * 16 + lrow;
    float bb = lu_b[e];
#pragma unroll
    for (int r = 0; r < 4; ++r) {
      size_t m = m0 + wave * 16 + qk * 4 + r;
      float lin = acc[nt][r] + bb;
      float gv = bf2f(g_buf[m * 128 + e]);
      out[m * 128 + e] = gv * lin;
    }
  }
}

extern "C" void kernel_launch(void* const* d_in, const int* in_sizes, int n_in,
                              void* d_out, int out_size, void* d_ws, size_t ws_size,
                              hipStream_t stream) {
  const float* pair = (const float*)d_in[0];
  const float* lng  = (const float*)d_in[1];
  const float* lnb  = (const float*)d_in[2];
  const float* ga_w = (const float*)d_in[3];
  const float* ga_b = (const float*)d_in[4];
  const float* la_w = (const float*)d_in[5];
  const float* la_b = (const float*)d_in[6];
  const float* gb_w = (const float*)d_in[7];
  const float* gb_b = (const float*)d_in[8];
  const float* lb_w = (const float*)d_in[9];
  const float* lb_b = (const float*)d_in[10];
  const float* g_w  = (const float*)d_in[11];
  const float* g_b  = (const float*)d_in[12];
  const float* lnug = (const float*)d_in[13];
  const float* lnub = (const float*)d_in[14];
  const float* lu_w = (const float*)d_in[15];
  const float* lu_b = (const float*)d_in[16];
  float* out = (float*)d_out;

  char* ws = (char*)d_ws;
  unsigned short* WT    = (unsigned short*)(ws);                  // 768*128*2   = 196608 B
  unsigned short* a_t   = (unsigned short*)(ws + 196608ull);      // 128*M*2     = 67108864 B
  unsigned short* b_t   = (unsigned short*)(ws + 67305472ull);    // 128*M*2
  unsigned short* g_buf = (unsigned short*)(ws + 134414336ull);   // M*128*2
  unsigned short* up_t  = (unsigned short*)(ws + 201523200ull);   // 128*M*2  (total ~268.6 MB)

  hipLaunchKernelGGL(prep_weights, dim3(384), dim3(256), 0, stream,
                     ga_w, la_w, gb_w, lb_w, g_w, lu_w, WT);
  hipLaunchKernelGGL(k1_proj, dim3(2048), dim3(512), 0, stream,
                     pair, lng, lnb, WT, ga_b, la_b, gb_b, lb_b, g_b, a_t, b_t, g_buf);
  hipLaunchKernelGGL(k2_einsum, dim3(16, 128), dim3(256), 0, stream, a_t, b_t, up_t);
  hipLaunchKernelGGL(k3_final, dim3(4096), dim3(256), 0, stream,
                     up_t, g_buf, WT, lnug, lnub, lu_b, out);
}

// Round 3
// 297.728 us; speedup vs baseline: 1.4916x; 1.0587x over previous
//
#include <hip/hip_runtime.h>
#include <hip/hip_bf16.h>

#define NN 512
#define MM (NN*NN)   // 262144 rows

typedef __attribute__((ext_vector_type(8))) unsigned short u16x8;
typedef __attribute__((ext_vector_type(4))) unsigned short u16x4;
typedef __attribute__((ext_vector_type(8))) __bf16 bf16x8;
typedef __attribute__((ext_vector_type(4))) float f32x4;

static __device__ __forceinline__ unsigned short f2bfi(float f) {
  return __builtin_bit_cast(unsigned short, __float2bfloat16(f));  // v_cvt_pk_bf16_f32 path
}
static __device__ __forceinline__ float bf2f(unsigned short h) {
  return __uint_as_float(((unsigned int)h) << 16);
}
static __device__ __forceinline__ bf16x8 ldfrag(const unsigned short* p) {
  u16x8 v = *(const u16x8*)p;
  return __builtin_bit_cast(bf16x8, v);
}
static __device__ __forceinline__ float sigm(float x) {
  return 1.0f / (1.0f + __expf(-x));
}

// ---------------- prep: WT[n][k] (bf16), n: [ga|la|gb|lb|g|lu] x 128 cols, k = 128 ----
__global__ void prep_weights(const float* __restrict__ ga_w, const float* __restrict__ la_w,
                             const float* __restrict__ gb_w, const float* __restrict__ lb_w,
                             const float* __restrict__ g_w,  const float* __restrict__ lu_w,
                             unsigned short* __restrict__ WT) {
  int idx = blockIdx.x * 256 + threadIdx.x;
  if (idx >= 768 * 128) return;
  int n = idx >> 7;     // output row (col of original weight)
  int k = idx & 127;    // reduction index
  int grp = n >> 7, cn = n & 127;
  const float* tabs[6] = {ga_w, la_w, gb_w, lb_w, g_w, lu_w};
  WT[idx] = f2bfi(tabs[grp][k * 128 + cn]);
}

// ---------------- K1: fused LN + 5 projections, double-buffered 2-phase schedule -------
// grid.x = M/128, block = 512 (8 waves); wave owns 16 rows x 128 cols per GEMM.
__global__ __launch_bounds__(512, 4) void k1_proj(
    const float* __restrict__ pair, const float* __restrict__ lng, const float* __restrict__ lnb,
    const unsigned short* __restrict__ WT,
    const float* __restrict__ ga_b, const float* __restrict__ la_b,
    const float* __restrict__ gb_b, const float* __restrict__ lb_b,
    const float* __restrict__ g_b,
    unsigned short* __restrict__ a_t, unsigned short* __restrict__ b_t,
    unsigned short* __restrict__ g_buf) {
  __shared__ __align__(16) unsigned short W0[128 * 136];
  __shared__ __align__(16) unsigned short W1[128 * 136];
  const int t = threadIdx.x;
  const size_t m0 = (size_t)blockIdx.x * 128;
  const int wave = t >> 6, lane = t & 63, lrow = lane & 15, qk = lane >> 4;
  const int rbase = t >> 4, off_ = (t & 15) * 8;

  u16x8 rga[4], rla[4], rgb[4], rlb[4], rg[4];
  auto stage_ld = [&](u16x8* r, int base) {
#pragma unroll
    for (int it = 0; it < 4; ++it)
      r[it] = *(const u16x8*)(WT + (size_t)(base + it * 32 + rbase) * 128 + off_);
  };
  auto stage_st = [&](unsigned short* buf, const u16x8* r) {
#pragma unroll
    for (int it = 0; it < 4; ++it)
      *(u16x8*)(buf + (it * 32 + rbase) * 136 + off_) = r[it];
  };

  // issue first two weight loads before LN so HBM/L2 latency hides under LN math
  stage_ld(rga, 0);
  stage_ld(rla, 128);

  // ---- LN: 128 rows -> W0 (bf16) ----
  {
    const int row = t >> 2, q = t & 3;
    const float* pr = pair + (m0 + row) * 128 + q * 32;
    float vals[32];
    float s = 0.f, ss = 0.f;
#pragma unroll
    for (int it = 0; it < 8; ++it) {
      f32x4 v = *(const f32x4*)(pr + it * 4);
#pragma unroll
      for (int j = 0; j < 4; ++j) { float x = v[j]; vals[it * 4 + j] = x; s += x; ss += x * x; }
    }
    s += __shfl_xor(s, 1);  s += __shfl_xor(s, 2);
    ss += __shfl_xor(ss, 1); ss += __shfl_xor(ss, 2);
    const float mean = s * (1.f / 128.f);
    const float var  = ss * (1.f / 128.f) - mean * mean;
    const float rstd = rsqrtf(var + 1e-5f);
#pragma unroll
    for (int i = 0; i < 4; ++i) {
      u16x8 pk;
#pragma unroll
      for (int j = 0; j < 8; ++j) {
        int c = q * 32 + i * 8 + j;
        pk[j] = f2bfi((vals[i * 8 + j] - mean) * rstd * lng[c] + lnb[c]);
      }
      *(u16x8*)(W0 + row * 136 + q * 32 + i * 8) = pk;
    }
  }
  __syncthreads();                                            // b0: LN in W0

  bf16x8 af[4];
  f32x4 accg[8], accl[8];
  auto run_gemm = [&](const unsigned short* buf, f32x4* acc) {
#pragma unroll
    for (int nt = 0; nt < 8; ++nt)
#pragma unroll
      for (int r = 0; r < 4; ++r) acc[nt][r] = 0.f;
#pragma unroll
    for (int ks = 0; ks < 4; ++ks)
#pragma unroll
      for (int nt = 0; nt < 8; ++nt) {
        bf16x8 bv = ldfrag(buf + (nt * 16 + lrow) * 136 + ks * 32 + 8 * qk);
        acc[nt] = __builtin_amdgcn_mfma_f32_16x16x32_bf16(af[ks], bv, acc[nt], 0, 0, 0);
      }
  };
  auto epi_ab = [&](unsigned short* buf, const float* gbias, const float* lbias) {
#pragma unroll
    for (int nt = 0; nt < 8; ++nt) {
      int col = nt * 16 + lrow;
      float bg = gbias[col], bl = lbias[col];
      u16x4 pk;
#pragma unroll
      for (int r = 0; r < 4; ++r)
        pk[r] = f2bfi(sigm(accg[nt][r] + bg) * (accl[nt][r] + bl));
      *(u16x4*)(buf + col * 136 + wave * 16 + qk * 4) = pk;
    }
  };
  auto wout = [&](unsigned short* dst, const unsigned short* buf) {
#pragma unroll
    for (int it = 0; it < 4; ++it) {
      int idx = it * 512 + t;
      int col = idx >> 4, i = idx & 15;
      *(u16x8*)(dst + (size_t)col * MM + m0 + i * 8) = *(const u16x8*)(buf + col * 136 + i * 8);
    }
  };

  // phase1: A-fragments from W0; stage ga -> W1; issue gb loads
#pragma unroll
  for (int ks = 0; ks < 4; ++ks)
    af[ks] = ldfrag(W0 + (wave * 16 + lrow) * 136 + ks * 32 + 8 * qk);
  stage_st(W1, rga);
  stage_ld(rgb, 256);
  __syncthreads();                                            // b1
  // phase2: GEMM ga(W1); stage la -> W0; issue lb loads
  run_gemm(W1, accg);
  stage_st(W0, rla);
  stage_ld(rlb, 384);
  __syncthreads();                                            // b2
  // phase3: GEMM la(W0); stage gb -> W1; issue g loads
  run_gemm(W0, accl);
  stage_st(W1, rgb);
  stage_ld(rg, 512);
  __syncthreads();                                            // b3
  // phase4: epilogue a -> W0 (transposed [col][row])
  epi_ab(W0, ga_b, la_b);
  __syncthreads();                                            // b4
  // phase5: write a_t from W0; GEMM gb(W1)
  wout(a_t, W0);
  run_gemm(W1, accg);
  __syncthreads();                                            // b5
  // phase6: stage lb -> W0, g -> W1
  stage_st(W0, rlb);
  stage_st(W1, rg);
  __syncthreads();                                            // b6
  // phase7: GEMM lb(W0)
  run_gemm(W0, accl);
  __syncthreads();                                            // b7
  // phase8: epilogue b -> W0; GEMM g(W1) (accg consumed by epi first, then reused)
  epi_ab(W0, gb_b, lb_b);
  run_gemm(W1, accg);
  __syncthreads();                                            // b8
  // phase9: write b_t from W0; g direct global stores (rows in 32B segments, L2-combined)
  wout(b_t, W0);
#pragma unroll
  for (int nt = 0; nt < 8; ++nt) {
    int col = nt * 16 + lrow;
    float bg = g_b[col];
#pragma unroll
    for (int r = 0; r < 4; ++r)
      g_buf[(m0 + wave * 16 + qk * 4 + r) * 128 + col] = f2bfi(sigm(accg[nt][r] + bg));
  }
}

// ---------------- K2: channel-batched NT GEMM update_t[c] = A_c * B_c^T ----------------
// 1-D grid 2048 = 128 channels x 16 tiles, XCD-chunk swizzled; double-buffered k-loop.
__global__ __launch_bounds__(256) void k2_einsum(
    const unsigned short* __restrict__ a_t, const unsigned short* __restrict__ b_t,
    unsigned short* __restrict__ up_t) {
  __shared__ __align__(16) unsigned short sA[2][128 * 40];
  __shared__ __align__(16) unsigned short sB[2][128 * 40];
  const int t = threadIdx.x;
  // bijective XCD swizzle: xcd gets 256 consecutive work-ids = 16 whole channels
  const int wid = (blockIdx.x & 7) * 256 + (blockIdx.x >> 3);
  const int c = wid >> 4;
  const int i0 = ((wid >> 2) & 3) * 128, j0 = (wid & 3) * 128;
  const unsigned short* Ag = a_t + (size_t)c * MM + (size_t)i0 * 512;
  const unsigned short* Bg = b_t + (size_t)c * MM + (size_t)j0 * 512;
  const int wave = t >> 6, lane = t & 63, wr = wave >> 1, wc = wave & 1;
  const int lrow = lane & 15, qk = lane >> 4;
  const int srow = t >> 2, sq = t & 3;   // staging coords: rows srow, srow+64
  f32x4 acc[4][4];
#pragma unroll
  for (int i = 0; i < 4; ++i)
#pragma unroll
    for (int j = 0; j < 4; ++j)
#pragma unroll
      for (int r = 0; r < 4; ++r) acc[i][j][r] = 0.f;

  u16x8 ra[2], rb[2];
  auto tile_ld = [&](int k0) {
#pragma unroll
    for (int h = 0; h < 2; ++h) {
      int row = h * 64 + srow;
      ra[h] = *(const u16x8*)(Ag + (size_t)row * 512 + k0 + sq * 8);
      rb[h] = *(const u16x8*)(Bg + (size_t)row * 512 + k0 + sq * 8);
    }
  };
  auto tile_st = [&](int buf) {
#pragma unroll
    for (int h = 0; h < 2; ++h) {
      int row = h * 64 + srow;
      *(u16x8*)(sA[buf] + row * 40 + sq * 8) = ra[h];
      *(u16x8*)(sB[buf] + row * 40 + sq * 8) = rb[h];
    }
  };

  tile_ld(0);
  tile_st(0);
  __syncthreads();
  int cur = 0;
  for (int ks = 0; ks < 16; ++ks) {
    if (ks < 15) tile_ld((ks + 1) * 32);      // loads fly under MFMAs
    bf16x8 afr[4], bv[4];
#pragma unroll
    for (int mt = 0; mt < 4; ++mt)
      afr[mt] = ldfrag(sA[cur] + (wr * 64 + mt * 16 + lrow) * 40 + 8 * qk);
#pragma unroll
    for (int nt = 0; nt < 4; ++nt)
      bv[nt] = ldfrag(sB[cur] + (wc * 64 + nt * 16 + lrow) * 40 + 8 * qk);
#pragma unroll
    for (int mt = 0; mt < 4; ++mt)
#pragma unroll
      for (int nt = 0; nt < 4; ++nt)
        acc[mt][nt] = __builtin_amdgcn_mfma_f32_16x16x32_bf16(afr[mt], bv[nt], acc[mt][nt], 0, 0, 0);
    if (ks < 15) tile_st(cur ^ 1);
    __syncthreads();
    cur ^= 1;
  }
  unsigned short* up = up_t + (size_t)c * MM;
#pragma unroll
  for (int mt = 0; mt < 4; ++mt)
#pragma unroll
    for (int nt = 0; nt < 4; ++nt) {
      int col = j0 + wc * 64 + nt * 16 + lrow;
#pragma unroll
      for (int r = 0; r < 4; ++r) {
        int row = i0 + wr * 64 + mt * 16 + qk * 4 + r;
        up[(size_t)row * 512 + col] = f2bfi(acc[mt][nt][r]);
      }
    }
}

// ---------------- K3: LN(update) @ lu_w + lu_b, * g -> out -----------------------------
// grid.x = M/64
__global__ __launch_bounds__(256) void k3_final(
    const unsigned short* __restrict__ up_t, const unsigned short* __restrict__ g_buf,
    const unsigned short* __restrict__ WT,
    const float* __restrict__ lnug, const float* __restrict__ lnub,
    const float* __restrict__ lu_b, float* __restrict__ out) {
  __shared__ __align__(16) unsigned short sU[64 * 138];
  __shared__ __align__(16) unsigned short sA[64 * 136];
  __shared__ __align__(16) unsigned short sB[128 * 136];
  const int t = threadIdx.x;
  const size_t m0 = (size_t)blockIdx.x * 64;
  // load update tile: per channel c, 64 consecutive m (coalesced 128B runs)
#pragma unroll
  for (int it = 0; it < 4; ++it) {
    int idx = it * 256 + t;
    int c = idx >> 3, m8 = (idx & 7) * 8;
    u16x8 v = *(const u16x8*)(up_t + (size_t)c * MM + m0 + m8);
#pragma unroll
    for (int j = 0; j < 8; ++j) sU[(m8 + j) * 138 + c] = v[j];
  }
  // load lu_wT (WT rows 640..767)
#pragma unroll
  for (int it = 0; it < 8; ++it) {
    int idx = it * 256 + t;
    int n = idx >> 4, off = (idx & 15) * 8;
    *(u16x8*)(sB + n * 136 + off) = *(const u16x8*)(WT + (size_t)(640 + n) * 128 + off);
  }
  __syncthreads();
  {
    const int row = t >> 2, q = t & 3;
    float vals[32]; float s = 0.f, ss = 0.f;
#pragma unroll
    for (int jj = 0; jj < 32; ++jj) {
      int cc = q + jj * 4;
      float x = bf2f(sU[row * 138 + cc]);
      vals[jj] = x; s += x; ss += x * x;
    }
    s += __shfl_xor(s, 1);  s += __shfl_xor(s, 2);
    ss += __shfl_xor(ss, 1); ss += __shfl_xor(ss, 2);
    float mean = s * (1.f / 128.f);
    float var  = ss * (1.f / 128.f) - mean * mean;
    float rstd = rsqrtf(var + 1e-5f);
#pragma unroll
    for (int jj = 0; jj < 32; ++jj) {
      int cc = q + jj * 4;
      float zn = (vals[jj] - mean) * rstd * lnug[cc] + lnub[cc];
      sA[row * 136 + cc] = f2bfi(zn);
    }
  }
  __syncthreads();
  const int wave = t >> 6, lane = t & 63, lrow = lane & 15, qk = lane >> 4;
  f32x4 acc[8];
#pragma unroll
  for (int i = 0; i < 8; ++i)
#pragma unroll
    for (int r = 0; r < 4; ++r) acc[i][r] = 0.f;
#pragma unroll
  for (int ks = 0; ks < 4; ++ks) {
    int k0 = ks * 32;
    bf16x8 af = ldfrag(sA + (wave * 16 + lrow) * 136 + k0 + 8 * qk);
#pragma unroll
    for (int nt = 0; nt < 8; ++nt) {
      bf16x8 bv = ldfrag(sB + (nt * 16 + lrow) * 136 + k0 + 8 * qk);
      acc[nt] = __builtin_amdgcn_mfma_f32_16x16x32_bf16(af, bv, acc[nt], 0, 0, 0);
    }
  }
#pragma unroll
  for (int nt = 0; nt < 8; ++nt) {
    int e = nt * 16 + lrow;
    float bb = lu_b[e];
#pragma unroll
    for (int r = 0; r < 4; ++r) {
      size_t m = m0 + wave * 16 + qk * 4 + r;
      float lin = acc[nt][r] + bb;
      float gv = bf2f(g_buf[m * 128 + e]);
      out[m * 128 + e] = gv * lin;
    }
  }
}

extern "C" void kernel_launch(void* const* d_in, const int* in_sizes, int n_in,
                              void* d_out, int out_size, void* d_ws, size_t ws_size,
                              hipStream_t stream) {
  const float* pair = (const float*)d_in[0];
  const float* lng  = (const float*)d_in[1];
  const float* lnb  = (const float*)d_in[2];
  const float* ga_w = (const float*)d_in[3];
  const float* ga_b = (const float*)d_in[4];
  const float* la_w = (const float*)d_in[5];
  const float* la_b = (const float*)d_in[6];
  const float* gb_w = (const float*)d_in[7];
  const float* gb_b = (const float*)d_in[8];
  const float* lb_w = (const float*)d_in[9];
  const float* lb_b = (const float*)d_in[10];
  const float* g_w  = (const float*)d_in[11];
  const float* g_b  = (const float*)d_in[12];
  const float* lnug = (const float*)d_in[13];
  const float* lnub = (const float*)d_in[14];
  const float* lu_w = (const float*)d_in[15];
  const float* lu_b = (const float*)d_in[16];
  float* out = (float*)d_out;

  char* ws = (char*)d_ws;
  unsigned short* WT    = (unsigned short*)(ws);                  // 768*128*2   = 196608 B
  unsigned short* a_t   = (unsigned short*)(ws + 196608ull);      // 128*M*2     = 67108864 B
  unsigned short* b_t   = (unsigned short*)(ws + 67305472ull);    // 128*M*2
  unsigned short* g_buf = (unsigned short*)(ws + 134414336ull);   // M*128*2
  unsigned short* up_t  = (unsigned short*)(ws + 201523200ull);   // 128*M*2  (total ~268.6 MB)

  hipLaunchKernelGGL(prep_weights, dim3(384), dim3(256), 0, stream,
                     ga_w, la_w, gb_w, lb_w, g_w, lu_w, WT);
  hipLaunchKernelGGL(k1_proj, dim3(2048), dim3(512), 0, stream,
                     pair, lng, lnb, WT, ga_b, la_b, gb_b, lb_b, g_b, a_t, b_t, g_buf);
  hipLaunchKernelGGL(k2_einsum, dim3(2048), dim3(256), 0, stream, a_t, b_t, up_t);
  hipLaunchKernelGGL(k3_final, dim3(4096), dim3(256), 0, stream,
                     up_t, g_buf, WT, lnug, lnub, lu_b, out);
}